// Round 1
// 274.632 us; speedup vs baseline: 1.0340x; 1.0340x over previous
//
#include <hip/hip_runtime.h>
#include <stdint.h>

#define N_B 4
#define SEQ 2048
#define EMB 1024
#define NH  16
#define HD  64
#define NHT 64   // N_B * NH
#define BQ  128
#define BK  64

typedef __attribute__((ext_vector_type(8))) short bf16x8;
typedef __attribute__((ext_vector_type(4))) short bf16x4;
typedef __attribute__((ext_vector_type(4))) float f32x4;

// RNE float->bf16 (no NaN inputs in this problem)
__device__ __forceinline__ short f2bf(float x) {
  unsigned u = __float_as_uint(x);
  u += 0x7fffu + ((u >> 16) & 1u);
  return (short)(u >> 16);
}

// packed 2x f32 -> 2x bf16 in one uint (HW v_cvt_pk_bf16_f32 when available)
#if __has_builtin(__builtin_amdgcn_cvt_pk_bf16_f32)
typedef __attribute__((ext_vector_type(2))) __bf16 bf16v2;
__device__ __forceinline__ unsigned pkbf(float a, float b) {
  bf16v2 r = __builtin_amdgcn_cvt_pk_bf16_f32(a, b);
  union { bf16v2 v; unsigned u; } c; c.v = r; return c.u;
}
#else
__device__ __forceinline__ unsigned pkbf(float a, float b) {
  return (unsigned)(unsigned short)f2bf(a) | ((unsigned)(unsigned short)f2bf(b) << 16);
}
#endif

// async global->LDS, 16B per lane; lds dest must be wave-uniform (HW adds lane*16)
__device__ __forceinline__ void glds16(const short* g, short* l) {
  __builtin_amdgcn_global_load_lds(
      (const __attribute__((address_space(1))) unsigned int*)g,
      (__attribute__((address_space(3))) unsigned int*)l, 16, 0, 0);
}

// XOR swizzle: LDS chunk c (8 shorts, 16B) of row r holds global chunk c ^ (r&7).
// swz_src bakes in a 64-short row stride (packed tiles ONLY).
__device__ __forceinline__ int swz_src(int lane) {
  return (((lane & 7) ^ ((lane >> 3) & 7)) * 8) + ((lane >> 3) * 64);
}
__device__ __forceinline__ int swz_rd(int r, int k) {
  return r * 64 + ((k ^ (r & 7)) * 8);
}

// ---------------- fused: z=0..2 per-head projection (bf16 MFMA), z=3 W_out cvt ----
// Q output (z==0) is pre-scaled by log2(e)/sqrt(E) so attn can exp2 directly.
__global__ __launch_bounds__(256) void projm_kernel(
    const float* __restrict__ Xq, const float* __restrict__ Xk, const float* __restrict__ Xv,
    const float* __restrict__ Wq, const float* __restrict__ Wk, const float* __restrict__ Wv,
    short* __restrict__ Qp, short* __restrict__ Kp, short* __restrict__ Vp,
    const float* __restrict__ Wo, short* __restrict__ Wb) {
  int tid = threadIdx.x;
  int z = blockIdx.z;
  if (z == 3) {  // W_out fp32 -> bf16
    int flat = blockIdx.x + blockIdx.y * 16;
    int idx = (flat * 256 + tid) * 4;
    f32x4 v = *(const f32x4*)(Wo + idx);
    uint2 u; u.x = pkbf(v.x, v.y); u.y = pkbf(v.z, v.w);
    *(uint2*)(Wb + idx) = u;
    return;
  }
  const float* X = (z == 0) ? Xq : (z == 1) ? Xk : Xv;
  const float* W = (z == 0) ? Wq : (z == 1) ? Wk : Wv;
  short* out = (z == 0) ? Qp : (z == 1) ? Kp : Vp;
  int transposed = (z == 2);
  float oscale = (z == 0) ? 0.04508422f : 1.0f;  // log2(e)/sqrt(E) folded into Q

  __shared__ __attribute__((aligned(16))) short Xs[128 * 64];  // swizzled
  __shared__ __attribute__((aligned(16))) short Ws[64 * 64];   // swizzled
  int w = tid >> 6, lane = tid & 63;
  int quad = lane >> 4, l15 = lane & 15;
  int sb = blockIdx.x * 128;
  int nh = blockIdx.y;
  int n = nh >> 4, h = nh & 15;
  int r4 = tid >> 2, c0 = (tid & 3) * 16;
  int ch0 = c0 >> 3;
#pragma unroll
  for (int rr = 0; rr < 2; rr++) {
    int row = rr * 64 + r4;
    const float* gp = X + ((size_t)(n * SEQ + sb + row)) * EMB + h * HD + c0;
    f32x4 a = *(const f32x4*)gp, b = *(const f32x4*)(gp + 4);
    f32x4 c = *(const f32x4*)(gp + 8), d = *(const f32x4*)(gp + 12);
    uint4 u0, u1;
    u0.x = pkbf(a.x, a.y); u0.y = pkbf(a.z, a.w);
    u0.z = pkbf(b.x, b.y); u0.w = pkbf(b.z, b.w);
    u1.x = pkbf(c.x, c.y); u1.y = pkbf(c.z, c.w);
    u1.z = pkbf(d.x, d.y); u1.w = pkbf(d.z, d.w);
    *(uint4*)&Xs[row * 64 + ((ch0 ^ (row & 7)) * 8)] = u0;
    *(uint4*)&Xs[row * 64 + (((ch0 + 1) ^ (row & 7)) * 8)] = u1;
  }
  {
    int e = r4;
    const float* wp = W + e * HD + c0;
    f32x4 a = *(const f32x4*)wp, b = *(const f32x4*)(wp + 4);
    f32x4 c = *(const f32x4*)(wp + 8), d = *(const f32x4*)(wp + 12);
    uint4 u0, u1;
    u0.x = pkbf(a.x, a.y); u0.y = pkbf(a.z, a.w);
    u0.z = pkbf(b.x, b.y); u0.w = pkbf(b.z, b.w);
    u1.x = pkbf(c.x, c.y); u1.y = pkbf(c.z, c.w);
    u1.z = pkbf(d.x, d.y); u1.w = pkbf(d.z, d.w);
    *(uint4*)&Ws[e * 64 + ((ch0 ^ (e & 7)) * 8)] = u0;
    *(uint4*)&Ws[e * 64 + (((ch0 + 1) ^ (e & 7)) * 8)] = u1;
  }
  __syncthreads();
  f32x4 acc[2][4] = {};
#pragma unroll
  for (int ch = 0; ch < 2; ch++) {
    bf16x8 af[2], bfr[4];
#pragma unroll
    for (int mi = 0; mi < 2; mi++)
      af[mi] = *(const bf16x8*)&Xs[swz_rd(w * 32 + mi * 16 + l15, ch * 4 + quad)];
#pragma unroll
    for (int ni = 0; ni < 4; ni++)
      bfr[ni] = *(const bf16x8*)&Ws[swz_rd(ni * 16 + l15, ch * 4 + quad)];
#pragma unroll
    for (int mi = 0; mi < 2; mi++)
#pragma unroll
      for (int ni = 0; ni < 4; ni++)
        acc[mi][ni] = __builtin_amdgcn_mfma_f32_16x16x32_bf16(af[mi], bfr[ni], acc[mi][ni], 0, 0, 0);
  }
  if (!transposed) {
#pragma unroll
    for (int mi = 0; mi < 2; mi++)
#pragma unroll
      for (int ni = 0; ni < 4; ni++)
#pragma unroll
        for (int r = 0; r < 4; r++) {
          int s = sb + w * 32 + mi * 16 + quad * 4 + r;
          out[((size_t)nh * SEQ + s) * HD + ni * 16 + l15] = f2bf(acc[mi][ni][r] * oscale);
        }
  } else {
#pragma unroll
    for (int mi = 0; mi < 2; mi++)
#pragma unroll
      for (int ni = 0; ni < 4; ni++) {
        int e2 = ni * 16 + l15;
        int s0 = sb + w * 32 + mi * 16 + quad * 4;
        uint2 u;
        u.x = pkbf(acc[mi][ni][0], acc[mi][ni][1]);
        u.y = pkbf(acc[mi][ni][2], acc[mi][ni][3]);
        *(uint2*)(out + ((size_t)nh * HD + e2) * SEQ + s0) = u;
      }
  }
}

// ---------------- flash attention: DOUBLE-buffered K/V, 40KB LDS, 4 blocks/CU ----
// One __syncthreads per K-tile: prefetch tile kt+1 at loop top, compute tile kt,
// barrier (implicit vmcnt(0) drain lands after ~2500cy of compute -> latency hidden).
// Q staging aliases buffer 1 (Q is register-resident before first prefetch).
// P bounce buffer halved: per kt, two kk-halves {QK^T(32kk) -> exp2 -> PV(ch)},
// per-wave 32x32 bf16 region with 4-chunk XOR swizzle.
// Q pre-scaled by log2(e)/sqrt(E) in projm -> exp2 directly (no v_mul).
__global__ __launch_bounds__(256, 4) void attn_kernel(
    const short* __restrict__ Qg, const short* __restrict__ Kg,
    const short* __restrict__ Vg, const int* __restrict__ maskp,
    short* __restrict__ AO) {
  // 40KB: [buf0: K 4096 | V 4096][buf1: K 4096 | V 4096][P 4096] (shorts)
  __shared__ __attribute__((aligned(16))) short L[20480];

  int tid = threadIdx.x;
  int w = tid >> 6, lane = tid & 63;
  int quad = lane >> 4, l15 = lane & 15;
  int nh = blockIdx.x;
  int qt0 = blockIdx.y * BQ;
  int n = nh >> 4, h = nh & 15;
  int ssrc = swz_src(lane);
  int vrow = lane >> 3;
  int vcg = (((lane & 7) ^ ((lane >> 3) & 7)) * 8);
  const int NT = SEQ / BK;

  const short* kb = Kg + (size_t)nh * SEQ * HD;
  const short* vb = Vg + (size_t)nh * HD * SEQ;
  short* Pw = &L[16384 + w * 1024];  // per-wave 32 rows x 32 kk

  // prologue: stage Q into buf1 alias region, K0/V0 into buf0
  const short* qbase = Qg + ((size_t)nh * SEQ + qt0) * HD;
#pragma unroll
  for (int i = 0; i < 4; i++) {
    int idx = (w * 4 + i) * 512;
    glds16(qbase + idx + ssrc, &L[8192 + idx]);
  }
#pragma unroll
  for (int i = 0; i < 2; i++) {
    int idx = (w * 2 + i) * 512;
    glds16(kb + idx + ssrc, &L[idx]);
    int d = (w * 2 + i) * 8 + vrow;
    glds16(vb + (size_t)d * SEQ + vcg, &L[4096 + idx]);
  }
  int mcur = maskp[n * SEQ + lane];  // tile 0 mask
  __syncthreads();
  bf16x8 qf[2][2];
#pragma unroll
  for (int nt = 0; nt < 2; nt++)
#pragma unroll
    for (int ch = 0; ch < 2; ch++)
      qf[nt][ch] = *(const bf16x8*)&L[8192 + swz_rd(w * 32 + nt * 16 + l15, ch * 4 + quad)];
  __syncthreads();  // all waves done reading Q -> buf1 free for prefetch

  bf16x8 vone;
#pragma unroll
  for (int j = 0; j < 8; j++) vone[j] = (short)0x3F80;  // bf16 1.0

  f32x4 Oacc[2][4] = {};
  f32x4 lacc[2] = {};

  for (int kt = 0; kt < NT; kt++) {
    int cur = kt & 1;
    const short* Kb = &L[cur * 8192];
    const short* Vb = &L[cur * 8192 + 4096];
    // prefetch kt+1 into the other buffer (no wait here)
    if (kt + 1 < NT) {
      size_t k0n = (size_t)(kt + 1) * BK;
      short* Kn = &L[(cur ^ 1) * 8192];
#pragma unroll
      for (int i = 0; i < 2; i++) {
        int idx = (w * 2 + i) * 512;
        glds16(kb + k0n * HD + idx + ssrc, &Kn[idx]);
        int d = (w * 2 + i) * 8 + vrow;
        glds16(vb + (size_t)d * SEQ + k0n + vcg, &Kn[4096 + idx]);
      }
    }
    int knx = (kt + 1 < NT) ? kt + 1 : kt;
    int mnxt = maskp[n * SEQ + knx * BK + lane];

    unsigned long long mb = __ballot(mcur != 0);
    bool anymask = (mb != ~0ull);

#pragma unroll
    for (int half = 0; half < 2; half++) {
      // S^T frags for kk in [half*32, half*32+32): row = kk, col = q (l15)
      f32x4 st[2][2];
      __builtin_amdgcn_s_setprio(1);
#pragma unroll
      for (int m2 = 0; m2 < 2; m2++) {
        int mt = half * 2 + m2;
        bf16x8 kf0 = *(const bf16x8*)&Kb[swz_rd(mt * 16 + l15, quad)];
        bf16x8 kf1 = *(const bf16x8*)&Kb[swz_rd(mt * 16 + l15, 4 + quad)];
#pragma unroll
        for (int nt = 0; nt < 2; nt++) {
          f32x4 a = {0.f, 0.f, 0.f, 0.f};
          a = __builtin_amdgcn_mfma_f32_16x16x32_bf16(kf0, qf[nt][0], a, 0, 0, 0);
          a = __builtin_amdgcn_mfma_f32_16x16x32_bf16(kf1, qf[nt][1], a, 0, 0, 0);
          st[m2][nt] = a;
        }
      }
      __builtin_amdgcn_s_setprio(0);
      if (anymask) {
#pragma unroll
        for (int m2 = 0; m2 < 2; m2++)
#pragma unroll
          for (int r = 0; r < 4; r++) {
            int kk = (half * 2 + m2) * 16 + quad * 4 + r;
            if (!((mb >> kk) & 1)) { st[m2][0][r] = -1e20f; st[m2][1][r] = -1e20f; }
          }
      }
      // exp2 + pack, P^T(C-layout) -> P(A-layout) via per-wave swizzled LDS half
#pragma unroll
      for (int nt = 0; nt < 2; nt++) {
        int row = nt * 16 + l15;
#pragma unroll
        for (int m2 = 0; m2 < 2; m2++) {
          float p0 = __builtin_amdgcn_exp2f(st[m2][nt][0]);
          float p1 = __builtin_amdgcn_exp2f(st[m2][nt][1]);
          float p2 = __builtin_amdgcn_exp2f(st[m2][nt][2]);
          float p3 = __builtin_amdgcn_exp2f(st[m2][nt][3]);
          uint2 u;
          u.x = pkbf(p0, p1);
          u.y = pkbf(p2, p3);
          int chunk = m2 * 2 + (quad >> 1);
          *(uint2*)&Pw[row * 32 + ((chunk ^ (row & 3)) * 8) + (quad & 1) * 4] = u;
        }
      }
      __builtin_amdgcn_wave_barrier();  // compiler-only: P writes before P reads

      // O += P @ V (this half's 32 kk); l += P @ ones (free l-sum on MFMA pipe)
      __builtin_amdgcn_s_setprio(1);
      bf16x8 pf[2];
#pragma unroll
      for (int qt = 0; qt < 2; qt++) {
        int row = qt * 16 + l15;
        pf[qt] = *(const bf16x8*)&Pw[row * 32 + ((quad ^ (row & 3)) * 8)];
      }
#pragma unroll
      for (int qt = 0; qt < 2; qt++)
        lacc[qt] = __builtin_amdgcn_mfma_f32_16x16x32_bf16(pf[qt], vone, lacc[qt], 0, 0, 0);
#pragma unroll
      for (int dt = 0; dt < 4; dt++) {
        bf16x8 vf = *(const bf16x8*)&Vb[swz_rd(dt * 16 + l15, half * 4 + quad)];
#pragma unroll
        for (int qt = 0; qt < 2; qt++)
          Oacc[qt][dt] = __builtin_amdgcn_mfma_f32_16x16x32_bf16(pf[qt], vf, Oacc[qt][dt], 0, 0, 0);
      }
      __builtin_amdgcn_s_setprio(0);
      __builtin_amdgcn_wave_barrier();  // P reads done before next half's writes
    }
    mcur = mnxt;
    __syncthreads();  // waves done with buf[cur]; prefetch to buf[cur^1] drained
  }
  // epilogue: lacc C-layout row == Oacc row -> per-lane divide, no shuffles
#pragma unroll
  for (int qt = 0; qt < 2; qt++)
#pragma unroll
    for (int r = 0; r < 4; r++) {
      float inv = 1.0f / lacc[qt][r];
      int qrow = qt0 + w * 32 + qt * 16 + quad * 4 + r;
      size_t rowb = ((size_t)n * SEQ + qrow) * EMB + h * HD;
#pragma unroll
      for (int dt = 0; dt < 4; dt++)
        AO[rowb + dt * 16 + l15] = f2bf(Oacc[qt][dt][r] * inv);
    }
}

// ---------------- out GEMM: C = AO @ Wb^T + bias (double-buffered) ----------------
__global__ __launch_bounds__(256, 2) void gemm_kernel(const short* __restrict__ A,
                                                      const short* __restrict__ B,
                                                      const float* __restrict__ bias,
                                                      float* __restrict__ C) {
  __shared__ __attribute__((aligned(16))) short As[2][128 * 64];
  __shared__ __attribute__((aligned(16))) short Bs[2][128 * 64];
  int tid = threadIdx.x;
  int w = tid >> 6, lane = tid & 63;
  int quad = lane >> 4, l15 = lane & 15;
  int m0 = blockIdx.x * 128, n0 = blockIdx.y * 128;
  int mw = (w & 1) * 64, nw = (w >> 1) * 64;
  int lrow = lane >> 3;
  int lcg = ((lane & 7) ^ ((lane >> 3) & 7)) * 8;
  f32x4 acc[4][4] = {};
#pragma unroll
  for (int i = 0; i < 4; i++) {
    int ii = w * 4 + i;
    int r = ii * 8 + lrow;
    glds16(A + (size_t)(m0 + r) * 1024 + lcg, &As[0][ii * 512]);
    glds16(B + (size_t)(n0 + r) * 1024 + lcg, &Bs[0][ii * 512]);
  }
  __syncthreads();
  for (int kt = 0; kt < 16; kt++) {
    int cur = kt & 1;
    if (kt < 15) {
      int k0n = (kt + 1) * 64;
#pragma unroll
      for (int i = 0; i < 4; i++) {
        int ii = w * 4 + i;
        int r = ii * 8 + lrow;
        glds16(A + (size_t)(m0 + r) * 1024 + k0n + lcg, &As[cur ^ 1][ii * 512]);
        glds16(B + (size_t)(n0 + r) * 1024 + k0n + lcg, &Bs[cur ^ 1][ii * 512]);
      }
    }
#pragma unroll
    for (int ch = 0; ch < 2; ch++) {
      bf16x8 af[4], bfr[4];
#pragma unroll
      for (int mi = 0; mi < 4; mi++)
        af[mi] = *(const bf16x8*)&As[cur][swz_rd(mw + mi * 16 + l15, ch * 4 + quad)];
#pragma unroll
      for (int ni = 0; ni < 4; ni++)
        bfr[ni] = *(const bf16x8*)&Bs[cur][swz_rd(nw + ni * 16 + l15, ch * 4 + quad)];
#pragma unroll
      for (int mi = 0; mi < 4; mi++)
#pragma unroll
        for (int ni = 0; ni < 4; ni++)
          acc[mi][ni] = __builtin_amdgcn_mfma_f32_16x16x32_bf16(af[mi], bfr[ni], acc[mi][ni], 0, 0, 0);
    }
    __syncthreads();
  }
#pragma unroll
  for (int ni = 0; ni < 4; ni++) {
    int col = n0 + nw + ni * 16 + l15;
    float bv = bias[col];
#pragma unroll
    for (int mi = 0; mi < 4; mi++) {
      int rb = m0 + mw + mi * 16 + quad * 4;
#pragma unroll
      for (int r = 0; r < 4; r++)
        C[(size_t)(rb + r) * 1024 + col] = acc[mi][ni][r] + bv;
    }
  }
}

extern "C" void kernel_launch(void* const* d_in, const int* in_sizes, int n_in,
                              void* d_out, int out_size, void* d_ws, size_t ws_size,
                              hipStream_t stream) {
  const float* values  = (const float*)d_in[0];
  const float* keys    = (const float*)d_in[1];
  const float* queries = (const float*)d_in[2];
  const int*   mask    = (const int*)d_in[3];
  const float* Wv = (const float*)d_in[4];
  const float* Wk = (const float*)d_in[5];
  const float* Wq = (const float*)d_in[6];
  const float* Wo = (const float*)d_in[7];
  const float* bo = (const float*)d_in[8];
  float* out = (float*)d_out;

  short* ws = (short*)d_ws;
  short* Qp = ws;
  short* Kp = Qp + (size_t)NHT * SEQ * HD;
  short* Vp = Kp + (size_t)NHT * SEQ * HD;
  short* AO = Vp + (size_t)NHT * SEQ * HD;
  short* Wb = AO + (size_t)N_B * SEQ * EMB;

  dim3 pg(SEQ / 128, NHT, 4);
  projm_kernel<<<pg, dim3(256), 0, stream>>>(queries, keys, values, Wq, Wk, Wv,
                                             Qp, Kp, Vp, Wo, Wb);
  dim3 ag(NHT, SEQ / BQ);
  attn_kernel<<<ag, dim3(256), 0, stream>>>(Qp, Kp, Vp, mask, AO);
  dim3 gg(8192 / 128, 1024 / 128);
  gemm_kernel<<<gg, dim3(256), 0, stream>>>(AO, Wb, bo, out);
}

// Round 3
// 265.397 us; speedup vs baseline: 1.0700x; 1.0348x over previous
//
#include <hip/hip_runtime.h>
#include <stdint.h>

#define N_B 4
#define SEQ 2048
#define EMB 1024
#define NH  16
#define HD  64
#define NHT 64   // N_B * NH
#define BQ  128
#define BK  64

typedef __attribute__((ext_vector_type(8))) short bf16x8;
typedef __attribute__((ext_vector_type(4))) float f32x4;
typedef __attribute__((ext_vector_type(2))) unsigned int u32x2;

// RNE float->bf16 (no NaN inputs in this problem)
__device__ __forceinline__ short f2bf(float x) {
  unsigned u = __float_as_uint(x);
  u += 0x7fffu + ((u >> 16) & 1u);
  return (short)(u >> 16);
}

// packed 2x f32 -> 2x bf16 in one uint (HW v_cvt_pk_bf16_f32 when available)
#if __has_builtin(__builtin_amdgcn_cvt_pk_bf16_f32)
typedef __attribute__((ext_vector_type(2))) __bf16 bf16v2;
__device__ __forceinline__ unsigned pkbf(float a, float b) {
  bf16v2 r = __builtin_amdgcn_cvt_pk_bf16_f32(a, b);
  union { bf16v2 v; unsigned u; } c; c.v = r; return c.u;
}
#else
__device__ __forceinline__ unsigned pkbf(float a, float b) {
  return (unsigned)(unsigned short)f2bf(a) | ((unsigned)(unsigned short)f2bf(b) << 16);
}
#endif

// cross-lane 32-swap: r0 = [a.lanes0-31, b.lanes0-31], r1 = [a.lanes32-63, b.lanes32-63]
__device__ __forceinline__ void swap32p(unsigned a, unsigned b, unsigned& r0, unsigned& r1) {
#if __has_builtin(__builtin_amdgcn_permlane32_swap)
  u32x2 r = __builtin_amdgcn_permlane32_swap(a, b, false, false);
  r0 = r[0]; r1 = r[1];
#else
  unsigned as = (unsigned)__shfl_xor((int)a, 32, 64), bs = (unsigned)__shfl_xor((int)b, 32, 64);
  int lo = (threadIdx.x & 32) == 0;
  r0 = lo ? a : bs;
  r1 = lo ? as : b;
#endif
}
// cross-lane 16-swap: r0 = [a.g0, b.g0, a.g2, b.g2], r1 = [a.g1, b.g1, a.g3, b.g3]
__device__ __forceinline__ void swap16p(unsigned a, unsigned b, unsigned& r0, unsigned& r1) {
#if __has_builtin(__builtin_amdgcn_permlane16_swap)
  u32x2 r = __builtin_amdgcn_permlane16_swap(a, b, false, false);
  r0 = r[0]; r1 = r[1];
#else
  unsigned as = (unsigned)__shfl_xor((int)a, 16, 64), bs = (unsigned)__shfl_xor((int)b, 16, 64);
  int ev = (threadIdx.x & 16) == 0;
  r0 = ev ? a : bs;
  r1 = ev ? as : b;
#endif
}

// async global->LDS, 16B per lane; lds dest must be wave-uniform (HW adds lane*16)
__device__ __forceinline__ void glds16(const short* g, short* l) {
  __builtin_amdgcn_global_load_lds(
      (const __attribute__((address_space(1))) unsigned int*)g,
      (__attribute__((address_space(3))) unsigned int*)l, 16, 0, 0);
}

// XOR swizzle: LDS chunk c (8 shorts, 16B) of row r holds global chunk c ^ (r&7).
// swz_src bakes in a 64-short row stride (packed tiles ONLY).
__device__ __forceinline__ int swz_src(int lane) {
  return (((lane & 7) ^ ((lane >> 3) & 7)) * 8) + ((lane >> 3) * 64);
}
__device__ __forceinline__ int swz_rd(int r, int k) {
  return r * 64 + ((k ^ (r & 7)) * 8);
}

// ---------------- fused: z=0..2 per-head projection (bf16 MFMA), z=3 W_out cvt ----
// Q output (z==0) is pre-scaled by log2(e)/sqrt(E) so attn can exp2 directly.
__global__ __launch_bounds__(256) void projm_kernel(
    const float* __restrict__ Xq, const float* __restrict__ Xk, const float* __restrict__ Xv,
    const float* __restrict__ Wq, const float* __restrict__ Wk, const float* __restrict__ Wv,
    short* __restrict__ Qp, short* __restrict__ Kp, short* __restrict__ Vp,
    const float* __restrict__ Wo, short* __restrict__ Wb) {
  int tid = threadIdx.x;
  int z = blockIdx.z;
  if (z == 3) {  // W_out fp32 -> bf16
    int flat = blockIdx.x + blockIdx.y * 16;
    int idx = (flat * 256 + tid) * 4;
    f32x4 v = *(const f32x4*)(Wo + idx);
    uint2 u; u.x = pkbf(v.x, v.y); u.y = pkbf(v.z, v.w);
    *(uint2*)(Wb + idx) = u;
    return;
  }
  const float* X = (z == 0) ? Xq : (z == 1) ? Xk : Xv;
  const float* W = (z == 0) ? Wq : (z == 1) ? Wk : Wv;
  short* out = (z == 0) ? Qp : (z == 1) ? Kp : Vp;
  int transposed = (z == 2);
  float oscale = (z == 0) ? 0.04508422f : 1.0f;  // log2(e)/sqrt(E) folded into Q

  __shared__ __attribute__((aligned(16))) short Xs[128 * 64];  // swizzled
  __shared__ __attribute__((aligned(16))) short Ws[64 * 64];   // swizzled
  int w = tid >> 6, lane = tid & 63;
  int quad = lane >> 4, l15 = lane & 15;
  int sb = blockIdx.x * 128;
  int nh = blockIdx.y;
  int n = nh >> 4, h = nh & 15;
  int r4 = tid >> 2, c0 = (tid & 3) * 16;
  int ch0 = c0 >> 3;
#pragma unroll
  for (int rr = 0; rr < 2; rr++) {
    int row = rr * 64 + r4;
    const float* gp = X + ((size_t)(n * SEQ + sb + row)) * EMB + h * HD + c0;
    f32x4 a = *(const f32x4*)gp, b = *(const f32x4*)(gp + 4);
    f32x4 c = *(const f32x4*)(gp + 8), d = *(const f32x4*)(gp + 12);
    uint4 u0, u1;
    u0.x = pkbf(a.x, a.y); u0.y = pkbf(a.z, a.w);
    u0.z = pkbf(b.x, b.y); u0.w = pkbf(b.z, b.w);
    u1.x = pkbf(c.x, c.y); u1.y = pkbf(c.z, c.w);
    u1.z = pkbf(d.x, d.y); u1.w = pkbf(d.z, d.w);
    *(uint4*)&Xs[row * 64 + ((ch0 ^ (row & 7)) * 8)] = u0;
    *(uint4*)&Xs[row * 64 + (((ch0 + 1) ^ (row & 7)) * 8)] = u1;
  }
  {
    int e = r4;
    const float* wp = W + e * HD + c0;
    f32x4 a = *(const f32x4*)wp, b = *(const f32x4*)(wp + 4);
    f32x4 c = *(const f32x4*)(wp + 8), d = *(const f32x4*)(wp + 12);
    uint4 u0, u1;
    u0.x = pkbf(a.x, a.y); u0.y = pkbf(a.z, a.w);
    u0.z = pkbf(b.x, b.y); u0.w = pkbf(b.z, b.w);
    u1.x = pkbf(c.x, c.y); u1.y = pkbf(c.z, c.w);
    u1.z = pkbf(d.x, d.y); u1.w = pkbf(d.z, d.w);
    *(uint4*)&Ws[e * 64 + ((ch0 ^ (e & 7)) * 8)] = u0;
    *(uint4*)&Ws[e * 64 + (((ch0 + 1) ^ (e & 7)) * 8)] = u1;
  }
  __syncthreads();
  f32x4 acc[2][4] = {};
#pragma unroll
  for (int ch = 0; ch < 2; ch++) {
    bf16x8 af[2], bfr[4];
#pragma unroll
    for (int mi = 0; mi < 2; mi++)
      af[mi] = *(const bf16x8*)&Xs[swz_rd(w * 32 + mi * 16 + l15, ch * 4 + quad)];
#pragma unroll
    for (int ni = 0; ni < 4; ni++)
      bfr[ni] = *(const bf16x8*)&Ws[swz_rd(ni * 16 + l15, ch * 4 + quad)];
#pragma unroll
    for (int mi = 0; mi < 2; mi++)
#pragma unroll
      for (int ni = 0; ni < 4; ni++)
        acc[mi][ni] = __builtin_amdgcn_mfma_f32_16x16x32_bf16(af[mi], bfr[ni], acc[mi][ni], 0, 0, 0);
  }
  if (!transposed) {
#pragma unroll
    for (int mi = 0; mi < 2; mi++)
#pragma unroll
      for (int ni = 0; ni < 4; ni++)
#pragma unroll
        for (int r = 0; r < 4; r++) {
          int s = sb + w * 32 + mi * 16 + quad * 4 + r;
          out[((size_t)nh * SEQ + s) * HD + ni * 16 + l15] = f2bf(acc[mi][ni][r] * oscale);
        }
  } else {
#pragma unroll
    for (int mi = 0; mi < 2; mi++)
#pragma unroll
      for (int ni = 0; ni < 4; ni++) {
        int e2 = ni * 16 + l15;
        int s0 = sb + w * 32 + mi * 16 + quad * 4;
        uint2 u;
        u.x = pkbf(acc[mi][ni][0], acc[mi][ni][1]);
        u.y = pkbf(acc[mi][ni][2], acc[mi][ni][3]);
        *(uint2*)(out + ((size_t)nh * HD + e2) * SEQ + s0) = u;
      }
  }
}

// ---------------- flash attention: double-buffered K/V, 32KB LDS, 4 blocks/CU ----
// One __syncthreads per K-tile (prefetch kt+1, compute kt, barrier drains prefetch
// after ~2800cy of compute). P never touches LDS: the C-layout -> A-layout
// redistribution is done in-register with permlane32_swap + permlane16_swap
// (2 VALU ops per reg pair), eliminating the P bounce buffer, its 4-way bank
// conflicts, and 8KB/wave/kt of LDS-pipe traffic.
// Q pre-scaled by log2(e)/sqrt(E) in projm -> exp2 directly.
__global__ __launch_bounds__(256, 4) void attn_kernel(
    const short* __restrict__ Qg, const short* __restrict__ Kg,
    const short* __restrict__ Vg, const int* __restrict__ maskp,
    short* __restrict__ AO) {
  // 32KB: [buf0: K 4096 | V 4096][buf1: K 4096 | V 4096] (shorts)
  __shared__ __attribute__((aligned(16))) short L[16384];

  int tid = threadIdx.x;
  int w = tid >> 6, lane = tid & 63;
  int quad = lane >> 4, l15 = lane & 15;
  int nh = blockIdx.x;
  int qt0 = blockIdx.y * BQ;
  int n = nh >> 4, h = nh & 15;
  int ssrc = swz_src(lane);
  int vrow = lane >> 3;
  int vcg = (((lane & 7) ^ ((lane >> 3) & 7)) * 8);
  const int NT = SEQ / BK;

  const short* kb = Kg + (size_t)nh * SEQ * HD;
  const short* vb = Vg + (size_t)nh * HD * SEQ;

  // prologue: stage Q into buf1 alias region (read to regs, then freed), K0/V0 into buf0
  const short* qbase = Qg + ((size_t)nh * SEQ + qt0) * HD;
#pragma unroll
  for (int i = 0; i < 4; i++) {
    int idx = (w * 4 + i) * 512;
    glds16(qbase + idx + ssrc, &L[8192 + idx]);
  }
#pragma unroll
  for (int i = 0; i < 2; i++) {
    int idx = (w * 2 + i) * 512;
    glds16(kb + idx + ssrc, &L[idx]);
    int d = (w * 2 + i) * 8 + vrow;
    glds16(vb + (size_t)d * SEQ + vcg, &L[4096 + idx]);
  }
  int mcur = maskp[n * SEQ + lane];  // tile 0 mask
  __syncthreads();
  bf16x8 qf[2][2];
#pragma unroll
  for (int nt = 0; nt < 2; nt++)
#pragma unroll
    for (int ch = 0; ch < 2; ch++)
      qf[nt][ch] = *(const bf16x8*)&L[8192 + swz_rd(w * 32 + nt * 16 + l15, ch * 4 + quad)];
  __syncthreads();  // all waves done reading Q -> buf1 free for prefetch

  bf16x8 vone;
#pragma unroll
  for (int j = 0; j < 8; j++) vone[j] = (short)0x3F80;  // bf16 1.0

  f32x4 Oacc[2][4] = {};
  f32x4 lacc[2] = {};

  for (int kt = 0; kt < NT; kt++) {
    int cur = kt & 1;
    const short* Kb = &L[cur * 8192];
    const short* Vb = &L[cur * 8192 + 4096];
    // prefetch kt+1 into the other buffer (no wait here)
    if (kt + 1 < NT) {
      size_t k0n = (size_t)(kt + 1) * BK;
      short* Kn = &L[(cur ^ 1) * 8192];
#pragma unroll
      for (int i = 0; i < 2; i++) {
        int idx = (w * 2 + i) * 512;
        glds16(kb + k0n * HD + idx + ssrc, &Kn[idx]);
        int d = (w * 2 + i) * 8 + vrow;
        glds16(vb + (size_t)d * SEQ + k0n + vcg, &Kn[4096 + idx]);
      }
    }
    int knx = (kt + 1 < NT) ? kt + 1 : kt;
    int mnxt = maskp[n * SEQ + knx * BK + lane];

    unsigned long long mb = __ballot(mcur != 0);
    bool anymask = (mb != ~0ull);

#pragma unroll
    for (int half = 0; half < 2; half++) {
      // S^T frags for kk in [half*32, half*32+32): row = kk, col = q (l15)
      f32x4 st[2][2];
      __builtin_amdgcn_s_setprio(1);
#pragma unroll
      for (int m2 = 0; m2 < 2; m2++) {
        int mt = half * 2 + m2;
        bf16x8 kf0 = *(const bf16x8*)&Kb[swz_rd(mt * 16 + l15, quad)];
        bf16x8 kf1 = *(const bf16x8*)&Kb[swz_rd(mt * 16 + l15, 4 + quad)];
#pragma unroll
        for (int nt = 0; nt < 2; nt++) {
          f32x4 a = {0.f, 0.f, 0.f, 0.f};
          a = __builtin_amdgcn_mfma_f32_16x16x32_bf16(kf0, qf[nt][0], a, 0, 0, 0);
          a = __builtin_amdgcn_mfma_f32_16x16x32_bf16(kf1, qf[nt][1], a, 0, 0, 0);
          st[m2][nt] = a;
        }
      }
      __builtin_amdgcn_s_setprio(0);
      if (anymask) {
#pragma unroll
        for (int m2 = 0; m2 < 2; m2++)
#pragma unroll
          for (int r = 0; r < 4; r++) {
            int kk = (half * 2 + m2) * 16 + quad * 4 + r;
            if (!((mb >> kk) & 1)) { st[m2][0][r] = -1e20f; st[m2][1][r] = -1e20f; }
          }
      }
      // exp2 + pack, then in-register C->A layout redistribution:
      // source lane (q'=quad,l15): A0=P[kk=4q'+0,1] A1=P[4q'+2,3] (m2=0), B0/B1 (+16).
      // target lane (quad,l15) A-frag needs kk = quad*8+{0..7}:
      //   swap32(A,B) -> r0=[A.lo,B.lo], r1=[A.hi,B.hi]
      //   swap16(r0,r1) -> ([Aq0,Aq2,Bq0,Bq2], [Aq1,Aq3,Bq1,Bq3]) = pf regs
      bf16x8 pf[2];
#pragma unroll
      for (int nt = 0; nt < 2; nt++) {
        unsigned A0 = pkbf(__builtin_amdgcn_exp2f(st[0][nt][0]), __builtin_amdgcn_exp2f(st[0][nt][1]));
        unsigned A1 = pkbf(__builtin_amdgcn_exp2f(st[0][nt][2]), __builtin_amdgcn_exp2f(st[0][nt][3]));
        unsigned B0 = pkbf(__builtin_amdgcn_exp2f(st[1][nt][0]), __builtin_amdgcn_exp2f(st[1][nt][1]));
        unsigned B1 = pkbf(__builtin_amdgcn_exp2f(st[1][nt][2]), __builtin_amdgcn_exp2f(st[1][nt][3]));
        unsigned r0, r1, s0, s1, o0, o1, o2, o3;
        swap32p(A0, B0, r0, r1);
        swap16p(r0, r1, o0, o2);
        swap32p(A1, B1, s0, s1);
        swap16p(s0, s1, o1, o3);
        union { unsigned u[4]; bf16x8 v; } c;
        c.u[0] = o0; c.u[1] = o1; c.u[2] = o2; c.u[3] = o3;
        pf[nt] = c.v;
      }

      // O += P @ V (this half's 32 kk); l += P @ ones (free l-sum on MFMA pipe)
      __builtin_amdgcn_s_setprio(1);
#pragma unroll
      for (int qt = 0; qt < 2; qt++)
        lacc[qt] = __builtin_amdgcn_mfma_f32_16x16x32_bf16(pf[qt], vone, lacc[qt], 0, 0, 0);
#pragma unroll
      for (int dt = 0; dt < 4; dt++) {
        bf16x8 vf = *(const bf16x8*)&Vb[swz_rd(dt * 16 + l15, half * 4 + quad)];
#pragma unroll
        for (int qt = 0; qt < 2; qt++)
          Oacc[qt][dt] = __builtin_amdgcn_mfma_f32_16x16x32_bf16(pf[qt], vf, Oacc[qt][dt], 0, 0, 0);
      }
      __builtin_amdgcn_s_setprio(0);
    }
    mcur = mnxt;
    __syncthreads();  // waves done with buf[cur]; prefetch to buf[cur^1] drained
  }
  // epilogue: lacc C-layout row == Oacc row -> per-lane divide, no shuffles
#pragma unroll
  for (int qt = 0; qt < 2; qt++)
#pragma unroll
    for (int r = 0; r < 4; r++) {
      float inv = 1.0f / lacc[qt][r];
      int qrow = qt0 + w * 32 + qt * 16 + quad * 4 + r;
      size_t rowb = ((size_t)n * SEQ + qrow) * EMB + h * HD;
#pragma unroll
      for (int dt = 0; dt < 4; dt++)
        AO[rowb + dt * 16 + l15] = f2bf(Oacc[qt][dt][r] * inv);
    }
}

// ---------------- out GEMM: C = AO @ Wb^T + bias (double-buffered) ----------------
__global__ __launch_bounds__(256, 2) void gemm_kernel(const short* __restrict__ A,
                                                      const short* __restrict__ B,
                                                      const float* __restrict__ bias,
                                                      float* __restrict__ C) {
  __shared__ __attribute__((aligned(16))) short As[2][128 * 64];
  __shared__ __attribute__((aligned(16))) short Bs[2][128 * 64];
  int tid = threadIdx.x;
  int w = tid >> 6, lane = tid & 63;
  int quad = lane >> 4, l15 = lane & 15;
  int m0 = blockIdx.x * 128, n0 = blockIdx.y * 128;
  int mw = (w & 1) * 64, nw = (w >> 1) * 64;
  int lrow = lane >> 3;
  int lcg = ((lane & 7) ^ ((lane >> 3) & 7)) * 8;
  f32x4 acc[4][4] = {};
#pragma unroll
  for (int i = 0; i < 4; i++) {
    int ii = w * 4 + i;
    int r = ii * 8 + lrow;
    glds16(A + (size_t)(m0 + r) * 1024 + lcg, &As[0][ii * 512]);
    glds16(B + (size_t)(n0 + r) * 1024 + lcg, &Bs[0][ii * 512]);
  }
  __syncthreads();
  for (int kt = 0; kt < 16; kt++) {
    int cur = kt & 1;
    if (kt < 15) {
      int k0n = (kt + 1) * 64;
#pragma unroll
      for (int i = 0; i < 4; i++) {
        int ii = w * 4 + i;
        int r = ii * 8 + lrow;
        glds16(A + (size_t)(m0 + r) * 1024 + k0n + lcg, &As[cur ^ 1][ii * 512]);
        glds16(B + (size_t)(n0 + r) * 1024 + k0n + lcg, &Bs[cur ^ 1][ii * 512]);
      }
    }
#pragma unroll
    for (int ch = 0; ch < 2; ch++) {
      bf16x8 af[4], bfr[4];
#pragma unroll
      for (int mi = 0; mi < 4; mi++)
        af[mi] = *(const bf16x8*)&As[cur][swz_rd(mw + mi * 16 + l15, ch * 4 + quad)];
#pragma unroll
      for (int ni = 0; ni < 4; ni++)
        bfr[ni] = *(const bf16x8*)&Bs[cur][swz_rd(nw + ni * 16 + l15, ch * 4 + quad)];
#pragma unroll
      for (int mi = 0; mi < 4; mi++)
#pragma unroll
        for (int ni = 0; ni < 4; ni++)
          acc[mi][ni] = __builtin_amdgcn_mfma_f32_16x16x32_bf16(af[mi], bfr[ni], acc[mi][ni], 0, 0, 0);
    }
    __syncthreads();
  }
#pragma unroll
  for (int ni = 0; ni < 4; ni++) {
    int col = n0 + nw + ni * 16 + l15;
    float bv = bias[col];
#pragma unroll
    for (int mi = 0; mi < 4; mi++) {
      int rb = m0 + mw + mi * 16 + quad * 4;
#pragma unroll
      for (int r = 0; r < 4; r++)
        C[(size_t)(rb + r) * 1024 + col] = acc[mi][ni][r] + bv;
    }
  }
}

extern "C" void kernel_launch(void* const* d_in, const int* in_sizes, int n_in,
                              void* d_out, int out_size, void* d_ws, size_t ws_size,
                              hipStream_t stream) {
  const float* values  = (const float*)d_in[0];
  const float* keys    = (const float*)d_in[1];
  const float* queries = (const float*)d_in[2];
  const int*   mask    = (const int*)d_in[3];
  const float* Wv = (const float*)d_in[4];
  const float* Wk = (const float*)d_in[5];
  const float* Wq = (const float*)d_in[6];
  const float* Wo = (const float*)d_in[7];
  const float* bo = (const float*)d_in[8];
  float* out = (float*)d_out;

  short* ws = (short*)d_ws;
  short* Qp = ws;
  short* Kp = Qp + (size_t)NHT * SEQ * HD;
  short* Vp = Kp + (size_t)NHT * SEQ * HD;
  short* AO = Vp + (size_t)NHT * SEQ * HD;
  short* Wb = AO + (size_t)N_B * SEQ * EMB;

  dim3 pg(SEQ / 128, NHT, 4);
  projm_kernel<<<pg, dim3(256), 0, stream>>>(queries, keys, values, Wq, Wk, Wv,
                                             Qp, Kp, Vp, Wo, Wb);
  dim3 ag(NHT, SEQ / BQ);
  attn_kernel<<<ag, dim3(256), 0, stream>>>(Qp, Kp, Vp, mask, AO);
  dim3 gg(8192 / 128, 1024 / 128);
  gemm_kernel<<<gg, dim3(256), 0, stream>>>(AO, Wb, bo, out);
}